// Round 11
// baseline (117.288 us; speedup 1.0000x reference)
//
#include <hip/hip_runtime.h>
#include <math.h>

static constexpr int Nb = 32;    // batch
static constexpr int Cc = 512;   // channels
static constexpr int Ss = 1024;  // spatial
static constexpr int Kk = 64;    // clusters
static constexpr int Dd = 256;   // out dim

typedef __attribute__((ext_vector_type(8))) short bf16x8;
typedef __attribute__((ext_vector_type(4))) float f32x4;
typedef __attribute__((ext_vector_type(4))) unsigned int u32x4;

union FragU { u32x4 u; bf16x8 h; };

__device__ __forceinline__ unsigned hi_pack(float x0, float x1) {
    return __builtin_amdgcn_perm(__float_as_uint(x1), __float_as_uint(x0), 0x07060302u);
}
__device__ __forceinline__ float trunc_hi(float x) {
    return __uint_as_float(__float_as_uint(x) & 0xFFFF0000u);
}
__device__ __forceinline__ void split8(const float* xv, FragU& bh, FragU& bl) {
#pragma unroll
    for (int p = 0; p < 4; ++p) {
        bh.u[p] = hi_pack(xv[2*p], xv[2*p+1]);
        float l0 = xv[2*p]   - trunc_hi(xv[2*p]);
        float l1 = xv[2*p+1] - trunc_hi(xv[2*p+1]);
        bl.u[p] = hi_pack(l0, l1);
    }
}

// async global->LDS, 16B/lane; LDS dest = wave-uniform base + lane*16 (HW)
__device__ __forceinline__ void gload_lds16(const void* g, void* l) {
    __builtin_amdgcn_global_load_lds(
        (const __attribute__((address_space(1))) void*)g,
        (__attribute__((address_space(3))) void*)l, 16, 0, 0);
}

// ---------------------------------------------------------------------------
// prep: split conv_w (64x512 f32) into bf16 hi/lo.
// ---------------------------------------------------------------------------
__global__ __launch_bounds__(256) void kprep_cw(
    const float* __restrict__ cw, short* __restrict__ cwh, short* __restrict__ cwl)
{
    int t = blockIdx.x * 256 + threadIdx.x;
    float4 v = *(const float4*)&cw[4 * (size_t)t];
    unsigned h0 = hi_pack(v.x, v.y), h1 = hi_pack(v.z, v.w);
    float l0 = v.x - trunc_hi(v.x), l1 = v.y - trunc_hi(v.y);
    float l2 = v.z - trunc_hi(v.z), l3 = v.w - trunc_hi(v.w);
    unsigned g0 = hi_pack(l0, l1), g1 = hi_pack(l2, l3);
    ((uint2*)cwh)[t] = make_uint2(h0, h1);
    ((uint2*)cwl)[t] = make_uint2(g0, g1);
}

// ---------------------------------------------------------------------------
// K1 (MFMA, counted-vmcnt 3-buffer pipeline): per tile ct (64 c): x-tile
// [64c][32s] f32 (8KB) + cw-tiles hi/lo [64k][64c] bf16 (8KB each), all via
// gload_lds (3 loads/tile/wave), vmcnt(3) keeps next 2 tiles in flight.
// cw-tile chunks XOR-swizzled (src-preswizzle, b128 frag reads 2-way banks).
// Wave w: m = w&3 (16 k's), sg = w>>2 (16 s-cols). In-register softmax.
// grid (32 stiles, 32 n) = 1024 blocks, block 512, LDS 73KB -> 2 blocks/CU.
// ---------------------------------------------------------------------------
__global__ __launch_bounds__(512) void k1_sa(
    const float* __restrict__ x, const short* __restrict__ cw_hi,
    const short* __restrict__ cw_lo, short* __restrict__ a_hi,
    short* __restrict__ a_lo, float* __restrict__ asum_part)
{
    __shared__ float xt[3 * 2048];      // [buf][64c][32s]
    __shared__ short cwh_t[3 * 4096];   // [buf][64k][64c]
    __shared__ short cwl_t[3 * 4096];
    __shared__ float redm[4][32];
    __shared__ float reds[4][32];

    const int tid = threadIdx.x;
    const int w = tid >> 6, lane = tid & 63;
    const int m = w & 3, sg = w >> 2;
    const int l15 = lane & 15, lg = lane >> 4;
    const int n = blockIdx.y, s0 = blockIdx.x * 32;

    // staging maps: lane stages row (8w + lane>>3), 16B chunk (lane&7)
    const int strow = lane >> 3;        // 0..7
    const int stchk = lane & 7;         // 0..7
    const int xrow = 8 * w + strow;     // c-local row (0..63)
    const int krow = 8 * w + strow;     // k row for cw tiles
    const int cwchk = stchk ^ (krow & 7);  // source pre-swizzle

    const float* xsrc = x + (size_t)n * Cc * Ss + s0 + 4 * stchk;

    auto GL = [&](int t) {
        const int b = t % 3;
        gload_lds16(xsrc + (size_t)(t * 64 + xrow) * Ss,
                    (char*)xt + b * 8192 + w * 1024);
        gload_lds16(cw_hi + (size_t)krow * Cc + t * 64 + cwchk * 8,
                    (char*)cwh_t + b * 8192 + w * 1024);
        gload_lds16(cw_lo + (size_t)krow * Cc + t * 64 + cwchk * 8,
                    (char*)cwl_t + b * 8192 + w * 1024);
    };

    f32x4 acc = {0.f, 0.f, 0.f, 0.f};
    float ssq = 0.f;
    const int sl = 16 * sg + l15;       // lane's s within tile

    GL(0);
    GL(1);

    for (int ct = 0; ct < 8; ++ct) {
        if (ct < 7) { asm volatile("s_waitcnt vmcnt(3)" ::: "memory"); }
        else        { asm volatile("s_waitcnt vmcnt(0)" ::: "memory"); }
        __builtin_amdgcn_sched_barrier(0);
        __builtin_amdgcn_s_barrier();
        __builtin_amdgcn_sched_barrier(0);

        const int b = ct % 3;
#pragma unroll
        for (int ks = 0; ks < 2; ++ks) {
            const int cb = 32 * ks + 8 * lg;
            float xv[8];
#pragma unroll
            for (int j = 0; j < 8; ++j) xv[j] = xt[b * 2048 + (cb + j) * 32 + sl];
#pragma unroll
            for (int j = 0; j < 8; ++j) ssq += xv[j] * xv[j];
            FragU bh, bl;
            split8(xv, bh, bl);
            FragU ah, al;
            const int cslot = ((4 * ks + lg) ^ (l15 & 7)) * 8;
            ah.u = *(const u32x4*)&cwh_t[b * 4096 + (16 * m + l15) * 64 + cslot];
            al.u = *(const u32x4*)&cwl_t[b * 4096 + (16 * m + l15) * 64 + cslot];
            acc = __builtin_amdgcn_mfma_f32_16x16x32_bf16(al.h, bh.h, acc, 0, 0, 0);
            acc = __builtin_amdgcn_mfma_f32_16x16x32_bf16(ah.h, bl.h, acc, 0, 0, 0);
            acc = __builtin_amdgcn_mfma_f32_16x16x32_bf16(ah.h, bh.h, acc, 0, 0, 0);
        }
        if (ct < 6) GL(ct + 2);
    }

    // per-s inverse L2 norm (lg groups covered disjoint c slices)
    ssq += __shfl_xor(ssq, 16);
    ssq += __shfl_xor(ssq, 32);
    const float inv = 1.f / fmaxf(sqrtf(ssq), 1e-12f);

    // softmax over 64 k: in-wave 16 k, cross-wave (4 m) via LDS
    float sv[4];
    float mmax = -1e30f;
#pragma unroll
    for (int r = 0; r < 4; ++r) {
        sv[r] = acc[r] * inv;
        mmax = fmaxf(mmax, sv[r]);
    }
    mmax = fmaxf(mmax, __shfl_xor(mmax, 16));
    mmax = fmaxf(mmax, __shfl_xor(mmax, 32));
    if (lg == 0) redm[m][sl] = mmax;
    __syncthreads();
    mmax = fmaxf(fmaxf(redm[0][sl], redm[1][sl]),
                 fmaxf(redm[2][sl], redm[3][sl]));
    float den = 0.f;
#pragma unroll
    for (int r = 0; r < 4; ++r) {
        sv[r] = expf(sv[r] - mmax);
        den += sv[r];
    }
    den += __shfl_xor(den, 16);
    den += __shfl_xor(den, 32);
    if (lg == 0) reds[m][sl] = den;
    __syncthreads();
    den = reds[0][sl] + reds[1][sl] + reds[2][sl] + reds[3][sl];
    const float rinv = 1.f / den;

    const int scol = s0 + sl;
#pragma unroll
    for (int r = 0; r < 4; ++r) {
        const float a = sv[r] * rinv;
        const int k = 16 * m + 4 * lg + r;
        float t = a;
        t += __shfl_xor(t, 1); t += __shfl_xor(t, 2);
        t += __shfl_xor(t, 4); t += __shfl_xor(t, 8);
        if (l15 == 0)
            asum_part[((size_t)(n * Kk + k) << 6) + blockIdx.x * 2 + sg] = t;
        const float av = a * inv;
        const unsigned u = __float_as_uint(av);
        const float hv = __uint_as_float(u & 0xFFFF0000u);
        const size_t idx = (size_t)(n * Kk + k) * Ss + scol;
        a_hi[idx] = (short)(u >> 16);
        a_lo[idx] = (short)(__float_as_uint(av - hv) >> 16);
    }
}

// ---------------------------------------------------------------------------
// kasum: asum[n][k] = sum of 64 partials.
// ---------------------------------------------------------------------------
__global__ __launch_bounds__(256) void kasum(
    const float* __restrict__ asum_part, float* __restrict__ asum)
{
    int row = blockIdx.x * 256 + threadIdx.x;
    const float* p = &asum_part[(size_t)row << 6];
    float s = 0.f;
#pragma unroll
    for (int i = 0; i < 16; ++i) {
        float4 v = *(const float4*)&p[4 * i];
        s += v.x + v.y + v.z + v.w;
    }
    asum[row] = s;
}

// ---------------------------------------------------------------------------
// K2 (MFMA, pipelined x-LDS + reg-prefetched a-frags): tile [64c][32s] f32,
// 3 bufs, 1 gload/tile/wave (vmcnt counts: 1 GL + 4 a-prefetch per iter ->
// wait vmcnt(5)). x chunks XOR-swizzled (b128 frag reads, spread banks).
// Wave w: wq = w&3 (16 c-cols), wh = w>>2 (m-pair) -> disjoint k, no combine.
// grid (32 n, 8 cp, 2 sh) = 512 blocks, block 512, LDS 24KB.
// ---------------------------------------------------------------------------
__global__ __launch_bounds__(512) void k2_vlad(
    const float* __restrict__ x, const short* __restrict__ a_hi,
    const short* __restrict__ a_lo, const float* __restrict__ centroids,
    const float* __restrict__ asum, float* __restrict__ vp0,
    float* __restrict__ vp1)
{
    __shared__ float xt[3 * 2048];    // [buf][64c][32s] swizzled chunks
    __shared__ float asum_l[64];

    const int tid = threadIdx.x;
    const int w = tid >> 6, lane = tid & 63;
    const int wq = w & 3, wh = w >> 2;
    const int l15 = lane & 15, lg = lane >> 4;
    const int n = blockIdx.x, cp = blockIdx.y, sh = blockIdx.z;

    if (sh == 1 && tid < 64) asum_l[tid] = asum[n * Kk + tid];

    // staging: lane stages c-row (8w + lane>>3), 16B chunk (lane&7)^(row&7)
    const int strow = lane >> 3;
    const int xrow = 8 * w + strow;
    const int stchk = (lane & 7) ^ (xrow & 7);
    const float* xsrc = x + (size_t)(n * Cc + cp * 64 + xrow) * Ss
                      + sh * 512 + 4 * stchk;

    auto GLx = [&](int t) {
        gload_lds16(xsrc + t * 32, (char*)xt + (t % 3) * 8192 + w * 1024);
    };

    const short* ahb = a_hi + (size_t)n * Kk * Ss + sh * 512;
    const short* alb = a_lo + (size_t)n * Kk * Ss + sh * 512;
    const int m0 = 2 * wh, m1 = 2 * wh + 1;
    const size_t arow0 = (size_t)(16 * m0 + l15) * Ss;
    const size_t arow1 = (size_t)(16 * m1 + l15) * Ss;

    f32x4 zero4 = {0.f, 0.f, 0.f, 0.f};
    f32x4 acc0 = zero4, acc1 = zero4;

    FragU ah0c, al0c, ah1c, al1c;      // current a-frags
    FragU ah0n, al0n, ah1n, al1n;      // next (prefetch)

    // prologue: 2 x-tiles + a(0)
    GLx(0);
    GLx(1);
    {
        const int so = 8 * lg;
        ah0c.u = *(const u32x4*)&ahb[arow0 + so];
        al0c.u = *(const u32x4*)&alb[arow0 + so];
        ah1c.u = *(const u32x4*)&ahb[arow1 + so];
        al1c.u = *(const u32x4*)&alb[arow1 + so];
    }

    for (int t = 0; t < 16; ++t) {
        if (t < 15) { asm volatile("s_waitcnt vmcnt(5)" ::: "memory"); }
        else        { asm volatile("s_waitcnt vmcnt(4)" ::: "memory"); }
        __builtin_amdgcn_sched_barrier(0);
        __builtin_amdgcn_s_barrier();
        __builtin_amdgcn_sched_barrier(0);

        if (t < 15) {                   // prefetch a(t+1)
            const int so = (t + 1) * 32 + 8 * lg;
            ah0n.u = *(const u32x4*)&ahb[arow0 + so];
            al0n.u = *(const u32x4*)&alb[arow0 + so];
            ah1n.u = *(const u32x4*)&ahb[arow1 + so];
            al1n.u = *(const u32x4*)&alb[arow1 + so];
        }

        // b-frag: 8 consecutive s of this lane's c-col from swizzled LDS
        const int b = t % 3;
        const int cl = 16 * wq + l15;
        const int q0 = (2 * lg)     ^ (l15 & 7);
        const int q1 = (2 * lg + 1) ^ (l15 & 7);
        float4 xq0 = *(const float4*)&xt[b * 2048 + cl * 32 + q0 * 4];
        float4 xq1 = *(const float4*)&xt[b * 2048 + cl * 32 + q1 * 4];
        float xv[8] = {xq0.x, xq0.y, xq0.z, xq0.w, xq1.x, xq1.y, xq1.z, xq1.w};
        FragU bh, bl;
        split8(xv, bh, bl);

        acc0 = __builtin_amdgcn_mfma_f32_16x16x32_bf16(al0c.h, bh.h, acc0, 0, 0, 0);
        acc0 = __builtin_amdgcn_mfma_f32_16x16x32_bf16(ah0c.h, bl.h, acc0, 0, 0, 0);
        acc0 = __builtin_amdgcn_mfma_f32_16x16x32_bf16(ah0c.h, bh.h, acc0, 0, 0, 0);
        acc1 = __builtin_amdgcn_mfma_f32_16x16x32_bf16(al1c.h, bh.h, acc1, 0, 0, 0);
        acc1 = __builtin_amdgcn_mfma_f32_16x16x32_bf16(ah1c.h, bl.h, acc1, 0, 0, 0);
        acc1 = __builtin_amdgcn_mfma_f32_16x16x32_bf16(ah1c.h, bh.h, acc1, 0, 0, 0);

        ah0c.u = ah0n.u; al0c.u = al0n.u;
        ah1c.u = ah1n.u; al1c.u = al1n.u;

        if (t < 14) GLx(t + 2);
    }

    float* dst = sh ? vp1 : vp0;
    const int c = cp * 64 + 16 * wq + l15;
#pragma unroll
    for (int mi = 0; mi < 2; ++mi) {
        const f32x4 a4 = mi ? acc1 : acc0;
        const int m = 2 * wh + mi;
#pragma unroll
        for (int r = 0; r < 4; ++r) {
            const int k = 16 * m + 4 * lg + r;
            float val = a4[r];
            if (sh == 1) val -= asum_l[k] * centroids[(size_t)k * Cc + c];
            dst[(size_t)(n * Kk + k) * Cc + c] = val;
        }
    }
}

// ---------------------------------------------------------------------------
// K3a: vlad = vp0 + vp1 (in place) + per-row norm.
// ---------------------------------------------------------------------------
__global__ __launch_bounds__(512) void k3a_norm(
    float* __restrict__ vlad, const float* __restrict__ vp1,
    float* __restrict__ nrm)
{
    const int tid = threadIdx.x;
    const int w = tid >> 6, lane = tid & 63;
    const int n = blockIdx.x, kg = blockIdx.y;
    const int row = (n * Kk) + kg * 8 + w;
    const size_t base = (size_t)row * Cc + lane * 8;

    float4 v0 = *(const float4*)&vlad[base];
    float4 v1 = *(const float4*)&vlad[base + 4];
    float4 u0 = *(const float4*)&vp1[base];
    float4 u1 = *(const float4*)&vp1[base + 4];
    v0.x += u0.x; v0.y += u0.y; v0.z += u0.z; v0.w += u0.w;
    v1.x += u1.x; v1.y += u1.y; v1.z += u1.z; v1.w += u1.w;
    *(float4*)&vlad[base] = v0;
    *(float4*)&vlad[base + 4] = v1;
    float ssq = v0.x*v0.x + v0.y*v0.y + v0.z*v0.z + v0.w*v0.w
              + v1.x*v1.x + v1.y*v1.y + v1.z*v1.z + v1.w*v1.w;
#pragma unroll
    for (int off = 32; off >= 1; off >>= 1) ssq += __shfl_xor(ssq, off);
    if (lane == 0) nrm[row] = sqrtf(ssq);
}

// ---------------------------------------------------------------------------
// K3b: scale[n][k] from nrm.
// ---------------------------------------------------------------------------
__global__ __launch_bounds__(64) void k3b_scale(
    const float* __restrict__ nrm, float* __restrict__ scale)
{
    const int n = blockIdx.x, k = threadIdx.x;
    float r = nrm[n * Kk + k];
    float rn = r / fmaxf(r, 1e-12f);
    float p = rn * rn;
#pragma unroll
    for (int off = 32; off >= 1; off >>= 1) p += __shfl_xor(p, off);
    float g = sqrtf(p);
    scale[n * Kk + k] = 1.f / (fmaxf(r, 1e-12f) * fmaxf(g, 1e-12f));
}

// ---------------------------------------------------------------------------
// K4: partial v over kc-chunk of 128 -> vpart[chunk][n][d]. float4 hw loads
// (4 d per lane), broadcast vl reads, float4 stores.
// grid 256, block 512 (8 waves; wave w owns n-group 4w..4w+3).
// ---------------------------------------------------------------------------
__global__ __launch_bounds__(512) void k4_hidden(
    const float* __restrict__ vlad, const float* __restrict__ scale,
    const float* __restrict__ hw, float* __restrict__ vpart)
{
    __shared__ float vl[128][33];
    __shared__ float scale_l[32];
    const int tid = threadIdx.x;
    const int kc0 = blockIdx.x * 128;
    const int k = kc0 >> 9;
    if (tid < 32) scale_l[tid] = scale[tid * Kk + k];
    __syncthreads();
#pragma unroll
    for (int i = 0; i < 8; ++i) {
        int idx = tid + i * 512;
        int nn = idx >> 7, kcl = idx & 127;
        vl[kcl][nn] = vlad[(size_t)nn * (Kk * Cc) + kc0 + kcl] * scale_l[nn];
    }
    __syncthreads();

    const int d4 = tid & 63, ng = tid >> 6;
    float4 acc4[4];
#pragma unroll
    for (int j = 0; j < 4; ++j) acc4[j] = make_float4(0.f, 0.f, 0.f, 0.f);

    for (int kcl = 0; kcl < 128; ++kcl) {
        const float4 wv = *(const float4*)&hw[(size_t)(kc0 + kcl) * Dd + d4 * 4];
#pragma unroll
        for (int j = 0; j < 4; ++j) {
            float vn = vl[kcl][4 * ng + j];
            acc4[j].x += vn * wv.x; acc4[j].y += vn * wv.y;
            acc4[j].z += vn * wv.z; acc4[j].w += vn * wv.w;
        }
    }
#pragma unroll
    for (int j = 0; j < 4; ++j)
        *(float4*)&vpart[((size_t)blockIdx.x * Nb + 4 * ng + j) * Dd + d4 * 4] = acc4[j];
}

// ---------------------------------------------------------------------------
// K5a: reduce 256 partial chunks -> v[n][d].
// ---------------------------------------------------------------------------
__global__ __launch_bounds__(128) void k5a_reduce(
    const float* __restrict__ vpart, float* __restrict__ v)
{
    int flat = blockIdx.x * 128 + threadIdx.x;
    float s = 0.f;
#pragma unroll 8
    for (int ch = 0; ch < 256; ++ch) s += vpart[(size_t)ch * (Nb * Dd) + flat];
    v[flat] = s;
}

// ---------------------------------------------------------------------------
// K5bc: fused BatchNorm + gating matmul.
// ---------------------------------------------------------------------------
__global__ __launch_bounds__(256) void k5bc_gate(
    const float* __restrict__ v, const float* __restrict__ gamma,
    const float* __restrict__ beta, const float* __restrict__ gw,
    float* __restrict__ v_bn, float* __restrict__ g_raw)
{
    __shared__ float vb[Dd];
    const int n = blockIdx.x, d = threadIdx.x;

    float s1 = 0.f;
#pragma unroll 8
    for (int i = 0; i < Nb; ++i) s1 += v[i * Dd + d];
    float mean = s1 * (1.f / Nb);
    float var = 0.f;
#pragma unroll 8
    for (int i = 0; i < Nb; ++i) {
        float t = v[i * Dd + d] - mean;
        var += t * t;
    }
    var *= (1.f / Nb);
    float inv = rsqrtf(var + 1e-5f);
    float vbn = (v[n * Dd + d] - mean) * inv * gamma[d] + beta[d];
    vb[d] = vbn;
    v_bn[n * Dd + d] = vbn;
    __syncthreads();

    float acc = 0.f;
#pragma unroll 8
    for (int c = 0; c < Dd; ++c) acc += vb[c] * gw[c * Dd + d];
    g_raw[n * Dd + d] = acc;
}

// ---------------------------------------------------------------------------
// K5d: gbn BatchNorm + sigmoid + multiply -> out.
// ---------------------------------------------------------------------------
__global__ __launch_bounds__(256) void k5d_out(
    const float* __restrict__ g_raw, const float* __restrict__ v_bn,
    const float* __restrict__ ggamma, const float* __restrict__ gbeta,
    float* __restrict__ out)
{
    const int d = threadIdx.x;
    float vals[Nb];
    float s1 = 0.f;
#pragma unroll
    for (int n = 0; n < Nb; ++n) {
        vals[n] = g_raw[n * Dd + d];
        s1 += vals[n];
    }
    float m = s1 * (1.f / Nb);
    float var = 0.f;
#pragma unroll
    for (int n = 0; n < Nb; ++n) {
        float t = vals[n] - m;
        var += t * t;
    }
    var *= (1.f / Nb);
    float inv = rsqrtf(var + 1e-5f);
    float g = ggamma[d], b = gbeta[d];
#pragma unroll
    for (int n = 0; n < Nb; ++n) {
        float t = (vals[n] - m) * inv * g + b;
        float sg = 1.f / (1.f + expf(-t));
        out[n * Dd + d] = v_bn[n * Dd + d] * sg;
    }
}

// ---------------------------------------------------------------------------
extern "C" void kernel_launch(void* const* d_in, const int* in_sizes, int n_in,
                              void* d_out, int out_size, void* d_ws, size_t ws_size,
                              hipStream_t stream)
{
    const float* x         = (const float*)d_in[0];
    const float* conv_w    = (const float*)d_in[1];
    const float* centroids = (const float*)d_in[2];
    const float* hidden_w  = (const float*)d_in[3];
    const float* bn2_gamma = (const float*)d_in[4];
    const float* bn2_beta  = (const float*)d_in[5];
    const float* gating_w  = (const float*)d_in[6];
    const float* gbn_gamma = (const float*)d_in[7];
    const float* gbn_beta  = (const float*)d_in[8];
    float* out = (float*)d_out;

    char* B = (char*)d_ws;
    short* a_hi      = (short*)(B);                          // 4 MB
    short* a_lo      = (short*)(B + (4u << 20));             // 4 MB
    float* vp0       = (float*)(B + (8u << 20));             // 4 MB (-> vlad)
    float* vp1       = (float*)(B + (12u << 20));            // 4 MB
    short* cw_hi     = (short*)(B + (16u << 20));            // 64 KB
    short* cw_lo     = (short*)(B + (16u << 20) + 65536u);   // 64 KB
    float* asum_part = (float*)(B + (16u << 20) + 131072u);  // 512 KB
    float* asum      = (float*)(B + (16u << 20) + 655360u);  // 8 KB
    float* nrm       = asum + 2048;                          // 8 KB
    float* scale     = nrm + 2048;
    float* v         = scale + 2048;
    float* v_bn      = v + 8192;
    float* g_raw     = v_bn + 8192;
    float* vpart     = (float*)B;   // alias a_hi/a_lo (dead after k2), 8 MB

    kprep_cw<<<32, 256, 0, stream>>>(conv_w, cw_hi, cw_lo);
    k1_sa<<<dim3(32, 32), 512, 0, stream>>>(x, cw_hi, cw_lo, a_hi, a_lo, asum_part);
    kasum<<<8, 256, 0, stream>>>(asum_part, asum);
    k2_vlad<<<dim3(32, 8, 2), 512, 0, stream>>>(x, a_hi, a_lo, centroids, asum, vp0, vp1);
    k3a_norm<<<dim3(32, 8), 512, 0, stream>>>(vp0, vp1, nrm);
    k3b_scale<<<32, 64, 0, stream>>>(nrm, scale);
    k4_hidden<<<256, 512, 0, stream>>>(vp0, scale, hidden_w, vpart);
    k5a_reduce<<<64, 128, 0, stream>>>(vpart, v);
    k5bc_gate<<<32, 256, 0, stream>>>(v, bn2_gamma, bn2_beta, gating_w, v_bn, g_raw);
    k5d_out<<<1, 256, 0, stream>>>(g_raw, v_bn, gbn_gamma, gbn_beta, out);
}

// Round 12
// 116.652 us; speedup vs baseline: 1.0055x; 1.0055x over previous
//
#include <hip/hip_runtime.h>
#include <math.h>

static constexpr int Nb = 32;    // batch
static constexpr int Cc = 512;   // channels
static constexpr int Ss = 1024;  // spatial
static constexpr int Kk = 64;    // clusters
static constexpr int Dd = 256;   // out dim

typedef __attribute__((ext_vector_type(8))) short bf16x8;
typedef __attribute__((ext_vector_type(4))) float f32x4;
typedef __attribute__((ext_vector_type(4))) unsigned int u32x4;

union FragU { u32x4 u; bf16x8 h; };

__device__ __forceinline__ unsigned hi_pack(float x0, float x1) {
    return __builtin_amdgcn_perm(__float_as_uint(x1), __float_as_uint(x0), 0x07060302u);
}
__device__ __forceinline__ float trunc_hi(float x) {
    return __uint_as_float(__float_as_uint(x) & 0xFFFF0000u);
}
__device__ __forceinline__ void split8(const float* xv, FragU& bh, FragU& bl) {
#pragma unroll
    for (int p = 0; p < 4; ++p) {
        bh.u[p] = hi_pack(xv[2*p], xv[2*p+1]);
        float l0 = xv[2*p]   - trunc_hi(xv[2*p]);
        float l1 = xv[2*p+1] - trunc_hi(xv[2*p+1]);
        bl.u[p] = hi_pack(l0, l1);
    }
}

// async global->LDS, 16B/lane; LDS dest = wave-uniform base + lane*16 (HW)
__device__ __forceinline__ void gload_lds16(const void* g, void* l) {
    __builtin_amdgcn_global_load_lds(
        (const __attribute__((address_space(1))) void*)g,
        (__attribute__((address_space(3))) void*)l, 16, 0, 0);
}

// ---------------------------------------------------------------------------
// prep: split conv_w (64x512 f32) into bf16 hi/lo.
// ---------------------------------------------------------------------------
__global__ __launch_bounds__(256) void kprep_cw(
    const float* __restrict__ cw, short* __restrict__ cwh, short* __restrict__ cwl)
{
    int t = blockIdx.x * 256 + threadIdx.x;
    float4 v = *(const float4*)&cw[4 * (size_t)t];
    unsigned h0 = hi_pack(v.x, v.y), h1 = hi_pack(v.z, v.w);
    float l0 = v.x - trunc_hi(v.x), l1 = v.y - trunc_hi(v.y);
    float l2 = v.z - trunc_hi(v.z), l3 = v.w - trunc_hi(v.w);
    unsigned g0 = hi_pack(l0, l1), g1 = hi_pack(l2, l3);
    ((uint2*)cwh)[t] = make_uint2(h0, h1);
    ((uint2*)cwl)[t] = make_uint2(g0, g1);
}

// ---------------------------------------------------------------------------
// K1 (MFMA, counted-vmcnt 3-buffer pipeline): unchanged from R11.
// grid (32 stiles, 32 n), block 512.
// ---------------------------------------------------------------------------
__global__ __launch_bounds__(512) void k1_sa(
    const float* __restrict__ x, const short* __restrict__ cw_hi,
    const short* __restrict__ cw_lo, short* __restrict__ a_hi,
    short* __restrict__ a_lo, float* __restrict__ asum_part)
{
    __shared__ float xt[3 * 2048];      // [buf][64c][32s]
    __shared__ short cwh_t[3 * 4096];   // [buf][64k][64c]
    __shared__ short cwl_t[3 * 4096];
    __shared__ float redm[4][32];
    __shared__ float reds[4][32];

    const int tid = threadIdx.x;
    const int w = tid >> 6, lane = tid & 63;
    const int m = w & 3, sg = w >> 2;
    const int l15 = lane & 15, lg = lane >> 4;
    const int n = blockIdx.y, s0 = blockIdx.x * 32;

    const int strow = lane >> 3;        // 0..7
    const int stchk = lane & 7;         // 0..7
    const int xrow = 8 * w + strow;     // c-local row (0..63)
    const int krow = 8 * w + strow;     // k row for cw tiles
    const int cwchk = stchk ^ (krow & 7);  // source pre-swizzle

    const float* xsrc = x + (size_t)n * Cc * Ss + s0 + 4 * stchk;

    auto GL = [&](int t) {
        const int b = t % 3;
        gload_lds16(xsrc + (size_t)(t * 64 + xrow) * Ss,
                    (char*)xt + b * 8192 + w * 1024);
        gload_lds16(cw_hi + (size_t)krow * Cc + t * 64 + cwchk * 8,
                    (char*)cwh_t + b * 8192 + w * 1024);
        gload_lds16(cw_lo + (size_t)krow * Cc + t * 64 + cwchk * 8,
                    (char*)cwl_t + b * 8192 + w * 1024);
    };

    f32x4 acc = {0.f, 0.f, 0.f, 0.f};
    float ssq = 0.f;
    const int sl = 16 * sg + l15;       // lane's s within tile

    GL(0);
    GL(1);

    for (int ct = 0; ct < 8; ++ct) {
        if (ct < 7) { asm volatile("s_waitcnt vmcnt(3)" ::: "memory"); }
        else        { asm volatile("s_waitcnt vmcnt(0)" ::: "memory"); }
        __builtin_amdgcn_sched_barrier(0);
        __builtin_amdgcn_s_barrier();
        __builtin_amdgcn_sched_barrier(0);

        const int b = ct % 3;
#pragma unroll
        for (int ks = 0; ks < 2; ++ks) {
            const int cb = 32 * ks + 8 * lg;
            float xv[8];
#pragma unroll
            for (int j = 0; j < 8; ++j) xv[j] = xt[b * 2048 + (cb + j) * 32 + sl];
#pragma unroll
            for (int j = 0; j < 8; ++j) ssq += xv[j] * xv[j];
            FragU bh, bl;
            split8(xv, bh, bl);
            FragU ah, al;
            const int cslot = ((4 * ks + lg) ^ (l15 & 7)) * 8;
            ah.u = *(const u32x4*)&cwh_t[b * 4096 + (16 * m + l15) * 64 + cslot];
            al.u = *(const u32x4*)&cwl_t[b * 4096 + (16 * m + l15) * 64 + cslot];
            acc = __builtin_amdgcn_mfma_f32_16x16x32_bf16(al.h, bh.h, acc, 0, 0, 0);
            acc = __builtin_amdgcn_mfma_f32_16x16x32_bf16(ah.h, bl.h, acc, 0, 0, 0);
            acc = __builtin_amdgcn_mfma_f32_16x16x32_bf16(ah.h, bh.h, acc, 0, 0, 0);
        }
        if (ct < 6) GL(ct + 2);
    }

    // per-s inverse L2 norm (lg groups covered disjoint c slices)
    ssq += __shfl_xor(ssq, 16);
    ssq += __shfl_xor(ssq, 32);
    const float inv = 1.f / fmaxf(sqrtf(ssq), 1e-12f);

    // softmax over 64 k: in-wave 16 k, cross-wave (4 m) via LDS
    float sv[4];
    float mmax = -1e30f;
#pragma unroll
    for (int r = 0; r < 4; ++r) {
        sv[r] = acc[r] * inv;
        mmax = fmaxf(mmax, sv[r]);
    }
    mmax = fmaxf(mmax, __shfl_xor(mmax, 16));
    mmax = fmaxf(mmax, __shfl_xor(mmax, 32));
    if (lg == 0) redm[m][sl] = mmax;
    __syncthreads();
    mmax = fmaxf(fmaxf(redm[0][sl], redm[1][sl]),
                 fmaxf(redm[2][sl], redm[3][sl]));
    float den = 0.f;
#pragma unroll
    for (int r = 0; r < 4; ++r) {
        sv[r] = expf(sv[r] - mmax);
        den += sv[r];
    }
    den += __shfl_xor(den, 16);
    den += __shfl_xor(den, 32);
    if (lg == 0) reds[m][sl] = den;
    __syncthreads();
    den = reds[0][sl] + reds[1][sl] + reds[2][sl] + reds[3][sl];
    const float rinv = 1.f / den;

    const int scol = s0 + sl;
#pragma unroll
    for (int r = 0; r < 4; ++r) {
        const float a = sv[r] * rinv;
        const int k = 16 * m + 4 * lg + r;
        float t = a;
        t += __shfl_xor(t, 1); t += __shfl_xor(t, 2);
        t += __shfl_xor(t, 4); t += __shfl_xor(t, 8);
        if (l15 == 0)
            asum_part[((size_t)(n * Kk + k) << 6) + blockIdx.x * 2 + sg] = t;
        const float av = a * inv;
        const unsigned u = __float_as_uint(av);
        const float hv = __uint_as_float(u & 0xFFFF0000u);
        const size_t idx = (size_t)(n * Kk + k) * Ss + scol;
        a_hi[idx] = (short)(u >> 16);
        a_lo[idx] = (short)(__float_as_uint(av - hv) >> 16);
    }
}

// ---------------------------------------------------------------------------
// K2' (MFMA, fused): full s-loop (32 tiles) in one block, asum reduced
// in-block from partials, centroid folded, writes final vlad + per-row ssq
// partials (for the norm). Pipeline identical to R11 k2 (3-buf x LDS +
// reg-prefetched a-frags, vmcnt(5)).
// Wave w: wq = w&3 (16 c-cols), wh = w>>2 (m-pair).
// grid (32 n, 8 cp) = 256 blocks, block 512.
// ---------------------------------------------------------------------------
__global__ __launch_bounds__(512) void k2_vlad(
    const float* __restrict__ x, const short* __restrict__ a_hi,
    const short* __restrict__ a_lo, const float* __restrict__ centroids,
    const float* __restrict__ asum_part, float* __restrict__ vlad,
    float* __restrict__ nrm_part)
{
    __shared__ float xt[3 * 2048];    // [buf][64c][32s] swizzled chunks
    __shared__ float asum_l[64];
    __shared__ float nssq[4][64];

    const int tid = threadIdx.x;
    const int w = tid >> 6, lane = tid & 63;
    const int wq = w & 3, wh = w >> 2;
    const int l15 = lane & 15, lg = lane >> 4;
    const int n = blockIdx.x, cp = blockIdx.y;

    if (tid < 64) {                     // fold kasum: sum 64 partials
        const float* p = &asum_part[(size_t)(n * Kk + tid) << 6];
        float s = 0.f;
#pragma unroll
        for (int i = 0; i < 16; ++i) {
            float4 q = *(const float4*)&p[4 * i];
            s += q.x + q.y + q.z + q.w;
        }
        asum_l[tid] = s;
    }

    // staging: lane stages c-row (8w + lane>>3), 16B chunk (lane&7)^(row&7)
    const int strow = lane >> 3;
    const int xrow = 8 * w + strow;
    const int stchk = (lane & 7) ^ (xrow & 7);
    const float* xsrc = x + (size_t)(n * Cc + cp * 64 + xrow) * Ss + 4 * stchk;

    auto GLx = [&](int t) {
        gload_lds16(xsrc + t * 32, (char*)xt + (t % 3) * 8192 + w * 1024);
    };

    const short* ahb = a_hi + (size_t)n * Kk * Ss;
    const short* alb = a_lo + (size_t)n * Kk * Ss;
    const int m0 = 2 * wh, m1 = 2 * wh + 1;
    const size_t arow0 = (size_t)(16 * m0 + l15) * Ss;
    const size_t arow1 = (size_t)(16 * m1 + l15) * Ss;

    f32x4 zero4 = {0.f, 0.f, 0.f, 0.f};
    f32x4 acc0 = zero4, acc1 = zero4;

    FragU ah0c, al0c, ah1c, al1c;      // current a-frags
    FragU ah0n, al0n, ah1n, al1n;      // next (prefetch)

    GLx(0);
    GLx(1);
    {
        const int so = 8 * lg;
        ah0c.u = *(const u32x4*)&ahb[arow0 + so];
        al0c.u = *(const u32x4*)&alb[arow0 + so];
        ah1c.u = *(const u32x4*)&ahb[arow1 + so];
        al1c.u = *(const u32x4*)&alb[arow1 + so];
    }

    for (int t = 0; t < 32; ++t) {
        if (t < 31) { asm volatile("s_waitcnt vmcnt(5)" ::: "memory"); }
        else        { asm volatile("s_waitcnt vmcnt(4)" ::: "memory"); }
        __builtin_amdgcn_sched_barrier(0);
        __builtin_amdgcn_s_barrier();
        __builtin_amdgcn_sched_barrier(0);

        if (t < 31) {                   // prefetch a(t+1)
            const int so = (t + 1) * 32 + 8 * lg;
            ah0n.u = *(const u32x4*)&ahb[arow0 + so];
            al0n.u = *(const u32x4*)&alb[arow0 + so];
            ah1n.u = *(const u32x4*)&ahb[arow1 + so];
            al1n.u = *(const u32x4*)&alb[arow1 + so];
        }

        const int b = t % 3;
        const int cl = 16 * wq + l15;
        const int q0 = (2 * lg)     ^ (l15 & 7);
        const int q1 = (2 * lg + 1) ^ (l15 & 7);
        float4 xq0 = *(const float4*)&xt[b * 2048 + cl * 32 + q0 * 4];
        float4 xq1 = *(const float4*)&xt[b * 2048 + cl * 32 + q1 * 4];
        float xv[8] = {xq0.x, xq0.y, xq0.z, xq0.w, xq1.x, xq1.y, xq1.z, xq1.w};
        FragU bh, bl;
        split8(xv, bh, bl);

        acc0 = __builtin_amdgcn_mfma_f32_16x16x32_bf16(al0c.h, bh.h, acc0, 0, 0, 0);
        acc0 = __builtin_amdgcn_mfma_f32_16x16x32_bf16(ah0c.h, bl.h, acc0, 0, 0, 0);
        acc0 = __builtin_amdgcn_mfma_f32_16x16x32_bf16(ah0c.h, bh.h, acc0, 0, 0, 0);
        acc1 = __builtin_amdgcn_mfma_f32_16x16x32_bf16(al1c.h, bh.h, acc1, 0, 0, 0);
        acc1 = __builtin_amdgcn_mfma_f32_16x16x32_bf16(ah1c.h, bl.h, acc1, 0, 0, 0);
        acc1 = __builtin_amdgcn_mfma_f32_16x16x32_bf16(ah1c.h, bh.h, acc1, 0, 0, 0);

        ah0c.u = ah0n.u; al0c.u = al0n.u;
        ah1c.u = ah1n.u; al1c.u = al1n.u;

        if (t < 30) GLx(t + 2);
    }

    // epilogue: centroid fold, vlad store, per-row ssq partials
    const int c = cp * 64 + 16 * wq + l15;
#pragma unroll
    for (int mi = 0; mi < 2; ++mi) {
        const f32x4 a4 = mi ? acc1 : acc0;
        const int m = 2 * wh + mi;
#pragma unroll
        for (int r = 0; r < 4; ++r) {
            const int k = 16 * m + 4 * lg + r;
            float val = a4[r] - asum_l[k] * centroids[(size_t)k * Cc + c];
            vlad[(size_t)(n * Kk + k) * Cc + c] = val;
            // reduce val^2 over the 16 c's of this lane-group
            float ss = val * val;
            ss += __shfl_xor(ss, 1); ss += __shfl_xor(ss, 2);
            ss += __shfl_xor(ss, 4); ss += __shfl_xor(ss, 8);
            if (l15 == 0) nssq[wq][k] = ss;
        }
    }
    __syncthreads();
    if (tid < 64) {
        float s = nssq[0][tid] + nssq[1][tid] + nssq[2][tid] + nssq[3][tid];
        nrm_part[((size_t)(n * Kk + tid) << 3) + cp] = s;
    }
}

// ---------------------------------------------------------------------------
// K3s: scale[n][k] from ssq partials. grid 32, block 64.
// ---------------------------------------------------------------------------
__global__ __launch_bounds__(64) void k3s_scale(
    const float* __restrict__ nrm_part, float* __restrict__ scale)
{
    const int n = blockIdx.x, k = threadIdx.x;
    const float* p = &nrm_part[(size_t)(n * Kk + k) << 3];
    float ssq = 0.f;
#pragma unroll
    for (int i = 0; i < 8; ++i) ssq += p[i];
    float r = sqrtf(ssq);
    float rn = r / fmaxf(r, 1e-12f);
    float pw = rn * rn;
#pragma unroll
    for (int off = 32; off >= 1; off >>= 1) pw += __shfl_xor(pw, off);
    float g = sqrtf(pw);
    scale[n * Kk + k] = 1.f / (fmaxf(r, 1e-12f) * fmaxf(g, 1e-12f));
}

// ---------------------------------------------------------------------------
// K4: partial v over kc-chunk of 128 -> vpart[chunk][n][d]. float4 hw loads.
// grid 256, block 512.
// ---------------------------------------------------------------------------
__global__ __launch_bounds__(512) void k4_hidden(
    const float* __restrict__ vlad, const float* __restrict__ scale,
    const float* __restrict__ hw, float* __restrict__ vpart)
{
    __shared__ float vl[128][33];
    __shared__ float scale_l[32];
    const int tid = threadIdx.x;
    const int kc0 = blockIdx.x * 128;
    const int k = kc0 >> 9;
    if (tid < 32) scale_l[tid] = scale[tid * Kk + k];
    __syncthreads();
#pragma unroll
    for (int i = 0; i < 8; ++i) {
        int idx = tid + i * 512;
        int nn = idx >> 7, kcl = idx & 127;
        vl[kcl][nn] = vlad[(size_t)nn * (Kk * Cc) + kc0 + kcl] * scale_l[nn];
    }
    __syncthreads();

    const int d4 = tid & 63, ng = tid >> 6;
    float4 acc4[4];
#pragma unroll
    for (int j = 0; j < 4; ++j) acc4[j] = make_float4(0.f, 0.f, 0.f, 0.f);

    for (int kcl = 0; kcl < 128; ++kcl) {
        const float4 wv = *(const float4*)&hw[(size_t)(kc0 + kcl) * Dd + d4 * 4];
#pragma unroll
        for (int j = 0; j < 4; ++j) {
            float vn = vl[kcl][4 * ng + j];
            acc4[j].x += vn * wv.x; acc4[j].y += vn * wv.y;
            acc4[j].z += vn * wv.z; acc4[j].w += vn * wv.w;
        }
    }
#pragma unroll
    for (int j = 0; j < 4; ++j)
        *(float4*)&vpart[((size_t)blockIdx.x * Nb + 4 * ng + j) * Dd + d4 * 4] = acc4[j];
}

// ---------------------------------------------------------------------------
// K5a: reduce 256 partial chunks -> v[n][d].
// ---------------------------------------------------------------------------
__global__ __launch_bounds__(128) void k5a_reduce(
    const float* __restrict__ vpart, float* __restrict__ v)
{
    int flat = blockIdx.x * 128 + threadIdx.x;
    float s = 0.f;
#pragma unroll 8
    for (int ch = 0; ch < 256; ++ch) s += vpart[(size_t)ch * (Nb * Dd) + flat];
    v[flat] = s;
}

// ---------------------------------------------------------------------------
// K5bc: fused BatchNorm + gating matmul.
// ---------------------------------------------------------------------------
__global__ __launch_bounds__(256) void k5bc_gate(
    const float* __restrict__ v, const float* __restrict__ gamma,
    const float* __restrict__ beta, const float* __restrict__ gw,
    float* __restrict__ v_bn, float* __restrict__ g_raw)
{
    __shared__ float vb[Dd];
    const int n = blockIdx.x, d = threadIdx.x;

    float s1 = 0.f;
#pragma unroll 8
    for (int i = 0; i < Nb; ++i) s1 += v[i * Dd + d];
    float mean = s1 * (1.f / Nb);
    float var = 0.f;
#pragma unroll 8
    for (int i = 0; i < Nb; ++i) {
        float t = v[i * Dd + d] - mean;
        var += t * t;
    }
    var *= (1.f / Nb);
    float inv = rsqrtf(var + 1e-5f);
    float vbn = (v[n * Dd + d] - mean) * inv * gamma[d] + beta[d];
    vb[d] = vbn;
    v_bn[n * Dd + d] = vbn;
    __syncthreads();

    float acc = 0.f;
#pragma unroll 8
    for (int c = 0; c < Dd; ++c) acc += vb[c] * gw[c * Dd + d];
    g_raw[n * Dd + d] = acc;
}

// ---------------------------------------------------------------------------
// K5d: gbn BatchNorm + sigmoid + multiply -> out.
// ---------------------------------------------------------------------------
__global__ __launch_bounds__(256) void k5d_out(
    const float* __restrict__ g_raw, const float* __restrict__ v_bn,
    const float* __restrict__ ggamma, const float* __restrict__ gbeta,
    float* __restrict__ out)
{
    const int d = threadIdx.x;
    float vals[Nb];
    float s1 = 0.f;
#pragma unroll
    for (int n = 0; n < Nb; ++n) {
        vals[n] = g_raw[n * Dd + d];
        s1 += vals[n];
    }
    float m = s1 * (1.f / Nb);
    float var = 0.f;
#pragma unroll
    for (int n = 0; n < Nb; ++n) {
        float t = vals[n] - m;
        var += t * t;
    }
    var *= (1.f / Nb);
    float inv = rsqrtf(var + 1e-5f);
    float g = ggamma[d], b = gbeta[d];
#pragma unroll
    for (int n = 0; n < Nb; ++n) {
        float t = (vals[n] - m) * inv * g + b;
        float sg = 1.f / (1.f + expf(-t));
        out[n * Dd + d] = v_bn[n * Dd + d] * sg;
    }
}

// ---------------------------------------------------------------------------
extern "C" void kernel_launch(void* const* d_in, const int* in_sizes, int n_in,
                              void* d_out, int out_size, void* d_ws, size_t ws_size,
                              hipStream_t stream)
{
    const float* x         = (const float*)d_in[0];
    const float* conv_w    = (const float*)d_in[1];
    const float* centroids = (const float*)d_in[2];
    const float* hidden_w  = (const float*)d_in[3];
    const float* bn2_gamma = (const float*)d_in[4];
    const float* bn2_beta  = (const float*)d_in[5];
    const float* gating_w  = (const float*)d_in[6];
    const float* gbn_gamma = (const float*)d_in[7];
    const float* gbn_beta  = (const float*)d_in[8];
    float* out = (float*)d_out;

    char* B = (char*)d_ws;
    short* a_hi      = (short*)(B);                          // 4 MB
    short* a_lo      = (short*)(B + (4u << 20));             // 4 MB
    float* vlad      = (float*)(B + (8u << 20));             // 4 MB
    short* cw_hi     = (short*)(B + (12u << 20));            // 64 KB
    short* cw_lo     = (short*)(B + (12u << 20) + 65536u);   // 64 KB
    float* asum_part = (float*)(B + (12u << 20) + 131072u);  // 512 KB
    float* nrm_part  = (float*)(B + (12u << 20) + 655360u);  // 64 KB
    float* scale     = (float*)(B + (12u << 20) + 720896u);  // 8 KB
    float* v         = scale + 2048;
    float* v_bn      = v + 8192;
    float* g_raw     = v_bn + 8192;
    float* vpart     = (float*)B;   // alias a_hi/a_lo (dead after k2), 8 MB

    kprep_cw<<<32, 256, 0, stream>>>(conv_w, cw_hi, cw_lo);
    k1_sa<<<dim3(32, 32), 512, 0, stream>>>(x, cw_hi, cw_lo, a_hi, a_lo, asum_part);
    k2_vlad<<<dim3(32, 8), 512, 0, stream>>>(x, a_hi, a_lo, centroids, asum_part, vlad, nrm_part);
    k3s_scale<<<32, 64, 0, stream>>>(nrm_part, scale);
    k4_hidden<<<256, 512, 0, stream>>>(vlad, scale, hidden_w, vpart);
    k5a_reduce<<<64, 128, 0, stream>>>(vpart, v);
    k5bc_gate<<<32, 256, 0, stream>>>(v, bn2_gamma, bn2_beta, gating_w, v_bn, g_raw);
    k5d_out<<<1, 256, 0, stream>>>(g_raw, v_bn, gbn_gamma, gbn_beta, out);
}